// Round 1
// baseline (573.068 us; speedup 1.0000x reference)
//
#include <hip/hip_runtime.h>
#include <math.h>

namespace {
constexpr int BB = 32, NPG = 4096, NTOT = BB*NPG, C = 128, FIN = 64, KK = 32, JJ = 40;
constexpr int YROWS = BB*JJ; // 1280
constexpr float EPS = 1e-5f;

// workspace layout (float offsets)
constexpr size_t X_OFF   = 0;                                  // N*C        (67.1 MB)
constexpr size_t I_OFF   = (size_t)NTOT*C;                     // N*J        (21.0 MB)
constexpr size_t TY_OFF  = I_OFF + (size_t)NTOT*JJ;            // 1280*128
constexpr size_t YP_OFF  = TY_OFF + (size_t)YROWS*C;           // 1280*32
constexpr size_t M_OFF   = YP_OFF + (size_t)YROWS*KK;          // 2*1280 (per-layer max)
constexpr size_t S_OFF   = M_OFF + 2*(size_t)YROWS;            // 2*1280 (per-layer sumexp)
constexpr size_t ST_OFF  = S_OFF + 2*(size_t)YROWS;            // 4 doubles (8 floats), 8B aligned
constexpr size_t NRM_OFF = ST_OFF + 8;                         // mx, rx, my, ry
constexpr size_t WS_FLOATS = NRM_OFF + 4;
}

// ---------------------------------------------------------------------------
// K1: out[r][c] = in[r][0:64] . W[c][0:64] + b[c]; accumulate sum/sumsq (double)
// 128 rows/block, 256 thr, 8x8 register tile, XOR-swizzled LDS (64KB exactly).
// ---------------------------------------------------------------------------
__global__ __launch_bounds__(256)
void k_gemm_in(const float* __restrict__ inp, const float* __restrict__ W,
               const float* __restrict__ bias, float* __restrict__ outp,
               double* __restrict__ stats) {
  __shared__ float smem[16384];          // 64 KiB: in_t[128][64] | w_l[128][64], both swizzled
  float* in_t = smem;
  float* w_l  = smem + 8192;
  const int t = threadIdx.x;
  const int r0 = blockIdx.x * 128;
  #pragma unroll
  for (int s = 0; s < 8; ++s) {
    int f = (t + 256*s) * 4;
    int r = f >> 6, d = f & 63;
    float4 v = *(const float4*)(inp + (size_t)r0*FIN + f);
    *(float4*)(in_t + r*64 + (d ^ ((r & 7) * 8))) = v;
    float4 w = *(const float4*)(W + f);
    *(float4*)(w_l + r*64 + (d ^ ((r & 7) * 8))) = w;
  }
  __syncthreads();
  const int rg = t >> 4;                 // rows r = rg + 16*i
  const int cg = t & 15;                 // cols c = cg + 16*j
  const int sw_i = (rg & 7) * 8;
  const int sw_w = (cg & 7) * 8;
  float acc[8][8];
  #pragma unroll
  for (int i=0;i<8;i++)
    #pragma unroll
    for (int j=0;j<8;j++) acc[i][j] = 0.f;
  #pragma unroll
  for (int dc = 0; dc < 16; ++dc) {
    const int d = dc*4;
    const int di = d ^ sw_i, dw = d ^ sw_w;
    float4 a[8], w4[8];
    #pragma unroll
    for (int i=0;i<8;i++) a[i]  = *(const float4*)(in_t + (rg+16*i)*64 + di);
    #pragma unroll
    for (int j=0;j<8;j++) w4[j] = *(const float4*)(w_l  + (cg+16*j)*64 + dw);
    #pragma unroll
    for (int i=0;i<8;i++)
      #pragma unroll
      for (int j=0;j<8;j++)
        acc[i][j] += a[i].x*w4[j].x + a[i].y*w4[j].y + a[i].z*w4[j].z + a[i].w*w4[j].w;
  }
  double ds = 0.0, dss = 0.0;
  #pragma unroll
  for (int i=0;i<8;i++) {
    const size_t r = (size_t)r0 + rg + 16*i;
    #pragma unroll
    for (int j=0;j<8;j++) {
      const int c = cg + 16*j;
      float v = acc[i][j] + bias[c];
      outp[r*C + c] = v;
      ds += (double)v; dss += (double)v*(double)v;
    }
  }
  #pragma unroll
  for (int off = 32; off > 0; off >>= 1) {
    ds  += __shfl_down(ds, off);
    dss += __shfl_down(dss, off);
  }
  __syncthreads();                        // in_t dead -> alias reduction buffer
  double* red = (double*)smem;
  if ((t & 63) == 0) { red[(t>>6)*2] = ds; red[(t>>6)*2+1] = dss; }
  __syncthreads();
  if (t == 0) {
    double a0 = red[0]+red[2]+red[4]+red[6];
    double a1 = red[1]+red[3]+red[5]+red[7];
    atomicAdd(stats+0, a0);
    atomicAdd(stats+1, a1);
  }
}

// ---------------------------------------------------------------------------
// K2: finalize global-LN stats for both tensors
// ---------------------------------------------------------------------------
__global__ void k_stats(const double* __restrict__ st, float* __restrict__ nrm) {
  if (threadIdx.x == 0) {
    double cx = (double)NTOT * (double)C;
    double mx = st[0]/cx, vx = st[1]/cx - mx*mx;
    nrm[0] = (float)mx;
    nrm[1] = (float)(1.0/sqrt(vx + (double)EPS));
    double cy = (double)YROWS * (double)C;
    double my = st[2]/cy, vy = st[3]/cy - my*my;
    nrm[2] = (float)my;
    nrm[3] = (float)(1.0/sqrt(vy + (double)EPS));
  }
}

// ---------------------------------------------------------------------------
// K3: y_p[row][k] = relu(q[k]*relu( ((ty-my)*ry) . V[:,k] )); 32 rows/block
// ---------------------------------------------------------------------------
__global__ __launch_bounds__(256)
void k_yp(const float* __restrict__ ty, const float* __restrict__ V,
          const float* __restrict__ q, const float* __restrict__ nrm,
          float* __restrict__ yp) {
  __shared__ float ty_l[32*132];
  __shared__ float vt_l[32*132];
  __shared__ float q_l[32];
  const int t = threadIdx.x;
  const int r0 = blockIdx.x * 32;
  const float my = nrm[2], ry = nrm[3];
  #pragma unroll
  for (int s=0;s<4;s++) {
    int f = (t + 256*s)*4;
    int r = f >> 7, d = f & 127;
    float4 v = *(const float4*)(ty + (size_t)(r0+r)*C + d);
    v.x = (v.x-my)*ry; v.y = (v.y-my)*ry; v.z = (v.z-my)*ry; v.w = (v.w-my)*ry;
    *(float4*)(ty_l + r*132 + d) = v;
  }
  #pragma unroll
  for (int s=0;s<4;s++) {                 // V[d][k] -> vt[k][d]
    int f = (t + 256*s)*4;
    int d = f >> 5, k = f & 31;
    float4 v = *(const float4*)(V + f);
    vt_l[(k+0)*132 + d] = v.x;
    vt_l[(k+1)*132 + d] = v.y;
    vt_l[(k+2)*132 + d] = v.z;
    vt_l[(k+3)*132 + d] = v.w;
  }
  if (t < 32) q_l[t] = q[t];
  __syncthreads();
  const int rg = t >> 3;                  // one row
  const int kg = t & 7;                   // k = kg + 8*j
  float acc[4] = {0.f,0.f,0.f,0.f};
  #pragma unroll
  for (int dc=0; dc<32; ++dc) {
    const int d = dc*4;
    float4 a = *(const float4*)(ty_l + rg*132 + d);
    #pragma unroll
    for (int j=0;j<4;j++) {
      float4 w = *(const float4*)(vt_l + (kg+8*j)*132 + d);
      acc[j] += a.x*w.x + a.y*w.y + a.z*w.z + a.w*w.w;
    }
  }
  #pragma unroll
  for (int j=0;j<4;j++) {
    const int k = kg + 8*j;
    float v = fmaxf(acc[j], 0.f);
    v = fmaxf(q_l[k]*v, 0.f);
    yp[(size_t)(r0+rg)*KK + k] = v;
  }
}

// ---------------------------------------------------------------------------
// K4 (MODE 0): x_p = relu(x@U), I = x_p@yp^T -> write I, atomicMax per-(b,j) max
// K4 (MODE 1): same + out = sigmoid(sum_j I^2)  [final-layer identity]
// 256 rows/block, d-chunked staging.
// ---------------------------------------------------------------------------
template<int MODE>
__global__ __launch_bounds__(256)
void k_xpI(const float* __restrict__ x, const float* __restrict__ U,
           const float* __restrict__ yp, const float* __restrict__ nrm,
           float* __restrict__ Iout, float* __restrict__ Mmax,
           float* __restrict__ outp, const int normFlag) {
  __shared__ float xt[256*36];            // 36864 B; aliased to x_p after GEMM
  __shared__ float ut[32*136];            // 17408 B; aliased to itile (64*44) later
  __shared__ float yp_l[40*36];           // 5760 B
  __shared__ float redm[40];
  const int t = threadIdx.x;
  const int bid = blockIdx.x;
  const int b  = bid >> 4;                // 16 blocks per graph
  const int n0 = (bid & 15) * 256;
  const size_t rowbase = (size_t)b*NPG + n0;
  float scale = 1.f, shift = 0.f;
  if (normFlag) { scale = nrm[1]; shift = -nrm[0]*nrm[1]; }
  #pragma unroll
  for (int s=0;s<4;s++) {                 // U[d][k] -> ut[k][d] (pad 136)
    int f = (t + 256*s)*4;
    int d = f >> 5, k = f & 31;
    float4 v = *(const float4*)(U + f);
    ut[(k+0)*136 + d] = v.x;
    ut[(k+1)*136 + d] = v.y;
    ut[(k+2)*136 + d] = v.z;
    ut[(k+3)*136 + d] = v.w;
  }
  for (int f4 = t; f4 < 320; f4 += 256) {
    int f = f4*4;
    *(float4*)(yp_l + (f>>5)*36 + (f&31)) = *(const float4*)(yp + (size_t)b*(JJ*KK) + f);
  }
  if (MODE == 0 && t < 40) redm[t] = 0.f;

  const int rg = t >> 3;                  // rows r = rg + 32*i, i<8
  const int kg = t & 7;                   // k = kg + 8*j, j<4
  float acc[8][4];
  #pragma unroll
  for (int i=0;i<8;i++)
    #pragma unroll
    for (int j=0;j<4;j++) acc[i][j] = 0.f;

  for (int cc = 0; cc < 4; ++cc) {
    const int d0 = cc*32;
    __syncthreads();
    #pragma unroll
    for (int s=0;s<8;s++) {               // stage 256x32 chunk of x (normalized)
      int f = (t + 256*s)*4;
      int r = f >> 5, dd = f & 31;
      float4 v = *(const float4*)(x + (rowbase + r)*C + d0 + dd);
      v.x = v.x*scale + shift; v.y = v.y*scale + shift;
      v.z = v.z*scale + shift; v.w = v.w*scale + shift;
      *(float4*)(xt + r*36 + dd) = v;
    }
    __syncthreads();
    #pragma unroll
    for (int dd4 = 0; dd4 < 8; ++dd4) {
      const int dd = dd4*4;
      float4 w4[4], a[8];
      #pragma unroll
      for (int j=0;j<4;j++) w4[j] = *(const float4*)(ut + (kg+8*j)*136 + d0 + dd);
      #pragma unroll
      for (int i=0;i<8;i++) a[i]  = *(const float4*)(xt + (rg+32*i)*36 + dd);
      #pragma unroll
      for (int i=0;i<8;i++)
        #pragma unroll
        for (int j=0;j<4;j++)
          acc[i][j] += a[i].x*w4[j].x + a[i].y*w4[j].y + a[i].z*w4[j].z + a[i].w*w4[j].w;
    }
  }
  __syncthreads();
  #pragma unroll
  for (int i=0;i<8;i++) {                 // x_p = relu(acc) -> xt alias
    const int r = rg + 32*i;
    #pragma unroll
    for (int j=0;j<4;j++)
      xt[r*36 + (kg + 8*j)] = fmaxf(acc[i][j], 0.f);
  }
  __syncthreads();
  // I phase: thread = (rg2 rows) x (jg of 4, j = jg + 4*s)
  const int rg2 = t >> 2;                 // rows r = rg2 + 64*i, i<4
  const int jg  = t & 3;
  float iacc[4][10];
  #pragma unroll
  for (int i=0;i<4;i++)
    #pragma unroll
    for (int s=0;s<10;s++) iacc[i][s] = 0.f;
  #pragma unroll
  for (int kc=0;kc<8;kc++) {
    const int kkk = kc*4;
    float4 ypv[10];
    #pragma unroll
    for (int s=0;s<10;s++) ypv[s] = *(const float4*)(yp_l + (jg+4*s)*36 + kkk);
    #pragma unroll
    for (int i=0;i<4;i++) {
      float4 xv = *(const float4*)(xt + (rg2+64*i)*36 + kkk);
      #pragma unroll
      for (int s=0;s<10;s++)
        iacc[i][s] += xv.x*ypv[s].x + xv.y*ypv[s].y + xv.z*ypv[s].z + xv.w*ypv[s].w;
    }
  }
  if (MODE == 0) {
    #pragma unroll
    for (int s=0;s<10;s++) {              // per-(b,j) max (I >= 0, int-compare valid)
      float m = iacc[0][s];
      #pragma unroll
      for (int i=1;i<4;i++) m = fmaxf(m, iacc[i][s]);
      atomicMax((int*)&redm[jg + 4*s], __float_as_int(m));
    }
    float* itile = ut;                    // ut dead -> 64x44 transpose staging
    #pragma unroll
    for (int i=0;i<4;i++) {
      __syncthreads();
      #pragma unroll
      for (int s=0;s<10;s++) itile[rg2*44 + jg + 4*s] = iacc[i][s];
      __syncthreads();
      #pragma unroll
      for (int u2=0; u2<10; ++u2) {       // coalesced copy to global
        int f = t + 256*u2;
        int r = f / 40, j = f - r*40;
        Iout[(rowbase + r + 64*i)*JJ + j] = itile[r*44 + j];
      }
    }
    __syncthreads();
    if (t < 40) atomicMax((int*)&Mmax[b*JJ + t], __float_as_int(redm[t]));
  } else {
    #pragma unroll
    for (int i=0;i<4;i++) {
      float oa = 0.f;
      #pragma unroll
      for (int s=0;s<10;s++) oa += iacc[i][s]*iacc[i][s];
      oa += __shfl_xor(oa, 1);
      oa += __shfl_xor(oa, 2);
      if (jg == 0) outp[rowbase + rg2 + 64*i] = 1.f/(1.f + __expf(-oa));
    }
  }
}

// ---------------------------------------------------------------------------
// K5: S[b][j] += sum_n exp(I - M); 256 nodes/block, wave shfl reduce + atomics
// ---------------------------------------------------------------------------
__global__ __launch_bounds__(256)
void k_sumexp(const float* __restrict__ Ibuf, const float* __restrict__ Mmax,
              float* __restrict__ Ssum) {
  __shared__ float M_l[40];
  const int t = threadIdx.x;
  const int bid = blockIdx.x;
  const int b = bid >> 4;
  const int n0 = (bid & 15) * 256;
  if (t < 40) M_l[t] = Mmax[b*JJ + t];
  __syncthreads();
  const size_t base = ((size_t)b*NPG + n0 + t) * JJ;
  const int lane = t & 63;
  #pragma unroll
  for (int f=0; f<10; ++f) {
    float4 v = *(const float4*)(Ibuf + base + f*4);
    float4 e;
    e.x = __expf(v.x - M_l[f*4+0]);
    e.y = __expf(v.y - M_l[f*4+1]);
    e.z = __expf(v.z - M_l[f*4+2]);
    e.w = __expf(v.w - M_l[f*4+3]);
    #pragma unroll
    for (int off=1; off<64; off<<=1) {
      e.x += __shfl_xor(e.x, off);
      e.y += __shfl_xor(e.y, off);
      e.z += __shfl_xor(e.z, off);
      e.w += __shfl_xor(e.w, off);
    }
    if (lane == 0) {
      atomicAdd(&Ssum[b*JJ + f*4+0], e.x);
      atomicAdd(&Ssum[b*JJ + f*4+1], e.y);
      atomicAdd(&Ssum[b*JJ + f*4+2], e.z);
      atomicAdd(&Ssum[b*JJ + f*4+3], e.w);
    }
  }
}

// ---------------------------------------------------------------------------
// K6: e = exp(I-M)/S; h = relu(e@yp); h2 = h@V^T; z = sigm([x,h2].gW + gb);
//     x = (1-z)x + z*h2   (in place). 128 rows/block.
// ---------------------------------------------------------------------------
__global__ __launch_bounds__(256)
void k_update(float* __restrict__ x, const float* __restrict__ Ibuf,
              const float* __restrict__ yp, const float* __restrict__ V,
              const float* __restrict__ gw, const float* __restrict__ gb,
              const float* __restrict__ Mmax, const float* __restrict__ Ssum,
              const float* __restrict__ nrm, const int normFlag) {
  __shared__ float e_l[128*40];           // 20480
  __shared__ float h_l[128*36];           // 18432
  __shared__ float v_l[128*36];           // 18432
  __shared__ float ypt[32*40];            // 5120
  __shared__ float M_l[40], Si_l[40];
  __shared__ float gx_l[128], gh_l[128];
  const int t = threadIdx.x;
  const int bid = blockIdx.x;
  const int b = bid >> 5;                 // 32 blocks per graph
  const int n0 = (bid & 31) * 128;
  const size_t rowbase = (size_t)b*NPG + n0;
  float scale = 1.f, shift = 0.f;
  if (normFlag) { scale = nrm[1]; shift = -nrm[0]*nrm[1]; }
  if (t < 40) { M_l[t] = Mmax[b*JJ + t]; Si_l[t] = 1.f / Ssum[b*JJ + t]; }
  if (t < 128) gx_l[t] = gw[t];
  else gh_l[t-128] = gw[t];
  for (int f4 = t; f4 < 320; f4 += 256) { // yp[b] -> ypt[k][j] (pad 40)
    int f = f4*4;
    int j = f >> 5;
    float4 v = *(const float4*)(yp + (size_t)b*(JJ*KK) + f);
    int k = f & 31;
    ypt[(k+0)*40 + j] = v.x;
    ypt[(k+1)*40 + j] = v.y;
    ypt[(k+2)*40 + j] = v.z;
    ypt[(k+3)*40 + j] = v.w;
  }
  #pragma unroll
  for (int s=0;s<4;s++) {                 // V[d][k] direct (pad 36)
    int f = (t + 256*s)*4;
    *(float4*)(v_l + (f>>5)*36 + (f&31)) = *(const float4*)(V + f);
  }
  __syncthreads();
  #pragma unroll
  for (int s=0;s<5;s++) {                 // e staging
    int f = (t + 256*s)*4;
    int n = f / 40, j = f - n*40;
    float4 v = *(const float4*)(Ibuf + (rowbase + n)*JJ + j);
    float4 e;
    e.x = __expf(v.x - M_l[j+0]) * Si_l[j+0];
    e.y = __expf(v.y - M_l[j+1]) * Si_l[j+1];
    e.z = __expf(v.z - M_l[j+2]) * Si_l[j+2];
    e.w = __expf(v.w - M_l[j+3]) * Si_l[j+3];
    *(float4*)(e_l + n*40 + j) = e;
  }
  __syncthreads();
  { // phase B: h[n][k] = relu(sum_j e*yp)
    const int rg = t >> 3;                // r = rg + 32*i, i<4
    const int kg = t & 7;                 // k = kg + 8*j2, j2<4
    float hacc[4][4];
    #pragma unroll
    for (int i=0;i<4;i++)
      #pragma unroll
      for (int j2=0;j2<4;j2++) hacc[i][j2] = 0.f;
    #pragma unroll
    for (int jc=0;jc<10;jc++) {
      const int jj = jc*4;
      float4 yv[4];
      #pragma unroll
      for (int j2=0;j2<4;j2++) yv[j2] = *(const float4*)(ypt + (kg+8*j2)*40 + jj);
      #pragma unroll
      for (int i=0;i<4;i++) {
        float4 ev = *(const float4*)(e_l + (rg+32*i)*40 + jj);
        #pragma unroll
        for (int j2=0;j2<4;j2++)
          hacc[i][j2] += ev.x*yv[j2].x + ev.y*yv[j2].y + ev.z*yv[j2].z + ev.w*yv[j2].w;
      }
    }
    #pragma unroll
    for (int i=0;i<4;i++)
      #pragma unroll
      for (int j2=0;j2<4;j2++)
        h_l[(rg+32*i)*36 + kg + 8*j2] = fmaxf(hacc[i][j2], 0.f);
  }
  __syncthreads();
  // phase C: h2 = h@V^T, gate, blend
  const int rg3 = t >> 4;                 // r = rg3 + 16*i, i<8
  const int cg  = t & 15;                 // c = cg + 16*j3, j3<8
  float h2[8][8];
  #pragma unroll
  for (int i=0;i<8;i++)
    #pragma unroll
    for (int j3=0;j3<8;j3++) h2[i][j3] = 0.f;
  #pragma unroll
  for (int kc=0;kc<8;kc++) {
    const int kk2 = kc*4;
    float4 vv[8];
    #pragma unroll
    for (int j3=0;j3<8;j3++) vv[j3] = *(const float4*)(v_l + (cg+16*j3)*36 + kk2);
    #pragma unroll
    for (int i=0;i<8;i++) {
      float4 hv = *(const float4*)(h_l + (rg3+16*i)*36 + kk2);
      #pragma unroll
      for (int j3=0;j3<8;j3++)
        h2[i][j3] += hv.x*vv[j3].x + hv.y*vv[j3].y + hv.z*vv[j3].z + hv.w*vv[j3].w;
    }
  }
  float xn[8][8];
  float gpv[8];
  #pragma unroll
  for (int i=0;i<8;i++) {
    float g = 0.f;
    const size_t rr = (rowbase + rg3 + 16*i)*C;
    #pragma unroll
    for (int j3=0;j3<8;j3++) {
      const int c = cg + 16*j3;
      float xv = x[rr + c]*scale + shift;
      xn[i][j3] = xv;
      g += gx_l[c]*xv + gh_l[c]*h2[i][j3];
    }
    gpv[i] = g;
  }
  #pragma unroll
  for (int i=0;i<8;i++) {                 // reduce over the 16 cg lanes
    gpv[i] += __shfl_xor(gpv[i], 1);
    gpv[i] += __shfl_xor(gpv[i], 2);
    gpv[i] += __shfl_xor(gpv[i], 4);
    gpv[i] += __shfl_xor(gpv[i], 8);
  }
  const float gbv = gb[0];
  #pragma unroll
  for (int i=0;i<8;i++) {
    const float z = 1.f/(1.f + __expf(-(gpv[i] + gbv)));
    const size_t rr = (rowbase + rg3 + 16*i)*C;
    #pragma unroll
    for (int j3=0;j3<8;j3++) {
      const int c = cg + 16*j3;
      x[rr + c] = (1.f - z)*xn[i][j3] + z*h2[i][j3];
    }
  }
}

extern "C" void kernel_launch(void* const* d_in, const int* in_sizes, int n_in,
                              void* d_out, int out_size, void* d_ws, size_t ws_size,
                              hipStream_t stream) {
  const float* nf  = (const float*)d_in[0];
  const float* fe  = (const float*)d_in[1];
  const float* W   = (const float*)d_in[2];
  const float* bin = (const float*)d_in[3];
  const float* U   = (const float*)d_in[4];
  const float* V   = (const float*)d_in[5];
  const float* q   = (const float*)d_in[6];
  const float* gw  = (const float*)d_in[7];
  const float* gb  = (const float*)d_in[8];
  float* out = (float*)d_out;
  float* wf  = (float*)d_ws;

  float*  X   = wf + X_OFF;
  float*  Ib  = wf + I_OFF;
  float*  TY  = wf + TY_OFF;
  float*  YP  = wf + YP_OFF;
  float*  M   = wf + M_OFF;
  float*  S   = wf + S_OFF;
  double* ST  = (double*)(wf + ST_OFF);
  float*  NRM = wf + NRM_OFF;

  // zero M/S/stats (I >= 0, so 0 is a valid max-init)
  hipMemsetAsync(M, 0, (WS_FLOATS - M_OFF)*sizeof(float), stream);

  k_gemm_in<<<NTOT/128, 256, 0, stream>>>(nf, W, bin, X, ST);
  k_gemm_in<<<YROWS/128, 256, 0, stream>>>(fe, W, bin, TY, ST+2);
  k_stats<<<1, 64, 0, stream>>>(ST, NRM);
  k_yp<<<YROWS/32, 256, 0, stream>>>(TY, V, q, NRM, YP);

  // layer 0
  k_xpI<0><<<512, 256, 0, stream>>>(X, U, YP, NRM, Ib, M, nullptr, 1);
  k_sumexp<<<512, 256, 0, stream>>>(Ib, M, S);
  k_update<<<1024, 256, 0, stream>>>(X, Ib, YP, V, gw, gb, M, S, NRM, 1);
  // layer 1
  k_xpI<0><<<512, 256, 0, stream>>>(X, U, YP, NRM, Ib, M+YROWS, nullptr, 0);
  k_sumexp<<<512, 256, 0, stream>>>(Ib, M+YROWS, S+YROWS);
  k_update<<<1024, 256, 0, stream>>>(X, Ib, YP, V, gw, gb, M+YROWS, S+YROWS, NRM, 0);
  // layer 2 (final): out = sigmoid(sum_j I^2), no I materialization
  k_xpI<1><<<512, 256, 0, stream>>>(X, U, YP, NRM, nullptr, nullptr, out, 0);
}

// Round 2
// 474.490 us; speedup vs baseline: 1.2078x; 1.2078x over previous
//
#include <hip/hip_runtime.h>
#include <math.h>

namespace {
constexpr int BB = 32, NPG = 4096, NTOT = BB*NPG, C = 128, FIN = 64, KK = 32, JJ = 40;
constexpr int YROWS = BB*JJ; // 1280
constexpr float EPS = 1e-5f;

// workspace layout (float offsets)
constexpr size_t X_OFF   = 0;                                  // N*C
constexpr size_t I_OFF   = (size_t)NTOT*C;                     // N*J
constexpr size_t TY_OFF  = I_OFF + (size_t)NTOT*JJ;            // 1280*128
constexpr size_t YP_OFF  = TY_OFF + (size_t)YROWS*C;           // 1280*32
constexpr size_t PM_OFF  = YP_OFF + (size_t)YROWS*KK;          // 32*40*32
constexpr size_t PS_OFF  = PM_OFF + 40960;                     // 32*40*32
constexpr size_t MG_OFF  = PS_OFF + 40960;                     // 1280
constexpr size_t SG_OFF  = MG_OFF + 1280;                      // 1280
constexpr size_t ST_OFF  = SG_OFF + 1280;                      // 4 doubles (8 floats)
constexpr size_t NRM_OFF = ST_OFF + 8;                         // mx, rx, my, ry
}

// ---------------------------------------------------------------------------
// K1: out[r][c] = in[r][0:64] . W[c][0:64] + b[c]; accumulate sum/sumsq (double)
// 64 rows/block, 256 thr, 4x8 register tile, XOR-swizzled LDS (48 KB -> 3/CU).
// ---------------------------------------------------------------------------
__global__ __launch_bounds__(256,3)
void k_gemm_in(const float* __restrict__ inp, const float* __restrict__ W,
               const float* __restrict__ bias, float* __restrict__ outp,
               double* __restrict__ stats) {
  __shared__ float in_t[64*64];          // 16384 B (aliased to red buffer at end)
  __shared__ float w_l[128*64];          // 32768 B
  const int t = threadIdx.x;
  const int r0 = blockIdx.x * 64;
  #pragma unroll
  for (int s = 0; s < 4; ++s) {
    int f = (t + 256*s) * 4;
    int r = f >> 6, d = f & 63;
    float4 v = *(const float4*)(inp + (size_t)r0*FIN + f);
    *(float4*)(in_t + r*64 + (d ^ ((r & 7) * 8))) = v;
  }
  #pragma unroll
  for (int s = 0; s < 8; ++s) {
    int f = (t + 256*s) * 4;
    int r = f >> 6, d = f & 63;
    float4 w = *(const float4*)(W + f);
    *(float4*)(w_l + r*64 + (d ^ ((r & 7) * 8))) = w;
  }
  __syncthreads();
  const int rg = t >> 4;                 // rows r = rg + 16*i, i<4
  const int cg = t & 15;                 // cols c = cg + 16*j, j<8
  const int swi = (rg & 7) * 8;
  const int sww = (cg & 7) * 8;
  float acc[4][8];
  #pragma unroll
  for (int i=0;i<4;i++)
    #pragma unroll
    for (int j=0;j<8;j++) acc[i][j] = 0.f;
  #pragma unroll
  for (int dc = 0; dc < 16; ++dc) {
    const int d = dc*4;
    const int di = d ^ swi, dw = d ^ sww;
    float4 a[4], w4[8];
    #pragma unroll
    for (int i=0;i<4;i++) a[i]  = *(const float4*)(in_t + (rg+16*i)*64 + di);
    #pragma unroll
    for (int j=0;j<8;j++) w4[j] = *(const float4*)(w_l  + (cg+16*j)*64 + dw);
    #pragma unroll
    for (int i=0;i<4;i++)
      #pragma unroll
      for (int j=0;j<8;j++)
        acc[i][j] += a[i].x*w4[j].x + a[i].y*w4[j].y + a[i].z*w4[j].z + a[i].w*w4[j].w;
  }
  double ds = 0.0, dss = 0.0;
  #pragma unroll
  for (int i=0;i<4;i++) {
    const size_t r = (size_t)r0 + rg + 16*i;
    #pragma unroll
    for (int j=0;j<8;j++) {
      const int c = cg + 16*j;
      float v = acc[i][j] + bias[c];
      outp[r*C + c] = v;
      ds += (double)v; dss += (double)v*(double)v;
    }
  }
  #pragma unroll
  for (int off = 32; off > 0; off >>= 1) {
    ds  += __shfl_down(ds, off);
    dss += __shfl_down(dss, off);
  }
  __syncthreads();                        // in_t dead -> alias reduction buffer
  double* red = (double*)in_t;
  if ((t & 63) == 0) { red[(t>>6)*2] = ds; red[(t>>6)*2+1] = dss; }
  __syncthreads();
  if (t == 0) {
    double a0 = red[0]+red[2]+red[4]+red[6];
    double a1 = red[1]+red[3]+red[5]+red[7];
    atomicAdd(stats+0, a0);
    atomicAdd(stats+1, a1);
  }
}

// ---------------------------------------------------------------------------
// K2: finalize global-LN stats for both tensors
// ---------------------------------------------------------------------------
__global__ void k_stats(const double* __restrict__ st, float* __restrict__ nrm) {
  if (threadIdx.x == 0) {
    double cx = (double)NTOT * (double)C;
    double mx = st[0]/cx, vx = st[1]/cx - mx*mx;
    nrm[0] = (float)mx;
    nrm[1] = (float)(1.0/sqrt(vx + (double)EPS));
    double cy = (double)YROWS * (double)C;
    double my = st[2]/cy, vy = st[3]/cy - my*my;
    nrm[2] = (float)my;
    nrm[3] = (float)(1.0/sqrt(vy + (double)EPS));
  }
}

// ---------------------------------------------------------------------------
// K3: y_p[row][k] = relu(q[k]*relu( ((ty-my)*ry) . V[:,k] )); 32 rows/block
// ---------------------------------------------------------------------------
__global__ __launch_bounds__(256)
void k_yp(const float* __restrict__ ty, const float* __restrict__ V,
          const float* __restrict__ q, const float* __restrict__ nrm,
          float* __restrict__ yp) {
  __shared__ float ty_l[32*132];
  __shared__ float vt_l[32*132];
  __shared__ float q_l[32];
  const int t = threadIdx.x;
  const int r0 = blockIdx.x * 32;
  const float my = nrm[2], ry = nrm[3];
  #pragma unroll
  for (int s=0;s<4;s++) {
    int f = (t + 256*s)*4;
    int r = f >> 7, d = f & 127;
    float4 v = *(const float4*)(ty + (size_t)(r0+r)*C + d);
    v.x = (v.x-my)*ry; v.y = (v.y-my)*ry; v.z = (v.z-my)*ry; v.w = (v.w-my)*ry;
    *(float4*)(ty_l + r*132 + d) = v;
  }
  #pragma unroll
  for (int s=0;s<4;s++) {                 // V[d][k] -> vt[k][d]
    int f = (t + 256*s)*4;
    int d = f >> 5, k = f & 31;
    float4 v = *(const float4*)(V + f);
    vt_l[(k+0)*132 + d] = v.x;
    vt_l[(k+1)*132 + d] = v.y;
    vt_l[(k+2)*132 + d] = v.z;
    vt_l[(k+3)*132 + d] = v.w;
  }
  if (t < 32) q_l[t] = q[t];
  __syncthreads();
  const int rg = t >> 3;                  // one row
  const int kg = t & 7;                   // k = kg + 8*j
  float acc[4] = {0.f,0.f,0.f,0.f};
  #pragma unroll
  for (int dc=0; dc<32; ++dc) {
    const int d = dc*4;
    float4 a = *(const float4*)(ty_l + rg*132 + d);
    #pragma unroll
    for (int j=0;j<4;j++) {
      float4 w = *(const float4*)(vt_l + (kg+8*j)*132 + d);
      acc[j] += a.x*w.x + a.y*w.y + a.z*w.z + a.w*w.w;
    }
  }
  #pragma unroll
  for (int j=0;j<4;j++) {
    const int k = kg + 8*j;
    float v = fmaxf(acc[j], 0.f);
    v = fmaxf(q_l[k]*v, 0.f);
    yp[(size_t)(r0+rg)*KK + k] = v;
  }
}

// ---------------------------------------------------------------------------
// K4 (MODE 0): x_p = relu(x@U), I = x_p@yp^T -> write I + per-block (m, sumexp)
// K4 (MODE 1): out = sigmoid(sum_j I^2)  [final-layer identity], no I write
// 128 rows/block, 41.9 KB LDS -> 3/CU, grid 1024.
// ---------------------------------------------------------------------------
template<int MODE>
__global__ __launch_bounds__(256,3)
void k_xpI(const float* __restrict__ x, const float* __restrict__ U,
           const float* __restrict__ yp, const float* __restrict__ nrm,
           float* __restrict__ Iout, float* __restrict__ Pm, float* __restrict__ Ps,
           float* __restrict__ outp, const int normFlag) {
  __shared__ float xt[128*36];            // 18432 B; aliased to x_p after GEMM
  __shared__ float ut[32*132];            // 16896 B; aliased to itile (64*44) later
  __shared__ float yp_l[40*36];           // 5760 B
  __shared__ float redm[40];
  __shared__ float sred[4*40];
  const int t = threadIdx.x;
  const int bid = blockIdx.x;
  const int b   = bid >> 5;               // 32 blocks per graph
  const int blk = bid & 31;
  const size_t rowbase = (size_t)b*NPG + blk*128;
  float scale = 1.f, shift = 0.f;
  if (normFlag) { scale = nrm[1]; shift = -nrm[0]*nrm[1]; }
  #pragma unroll
  for (int s=0;s<4;s++) {                 // U[d][k] -> ut[k][d] (stride 132)
    int f = (t + 256*s)*4;
    int d = f >> 5, k = f & 31;
    float4 v = *(const float4*)(U + f);
    ut[(k+0)*132 + d] = v.x;
    ut[(k+1)*132 + d] = v.y;
    ut[(k+2)*132 + d] = v.z;
    ut[(k+3)*132 + d] = v.w;
  }
  for (int f4 = t; f4 < 320; f4 += 256) {
    int f = f4*4;
    *(float4*)(yp_l + (f>>5)*36 + (f&31)) = *(const float4*)(yp + (size_t)b*(JJ*KK) + f);
  }
  if (MODE == 0 && t < 40) redm[t] = 0.f;

  const int rg = t >> 3;                  // rows r = rg + 32*i, i<4
  const int kg = t & 7;                   // k = kg + 8*j, j<4
  float acc[4][4];
  #pragma unroll
  for (int i=0;i<4;i++)
    #pragma unroll
    for (int j=0;j<4;j++) acc[i][j] = 0.f;

  for (int cc = 0; cc < 4; ++cc) {
    const int d0 = cc*32;
    __syncthreads();
    #pragma unroll
    for (int s=0;s<4;s++) {               // stage 128x32 chunk of x (normalized)
      int f = (t + 256*s)*4;
      int r = f >> 5, dd = f & 31;
      float4 v = *(const float4*)(x + (rowbase + r)*C + d0 + dd);
      v.x = v.x*scale + shift; v.y = v.y*scale + shift;
      v.z = v.z*scale + shift; v.w = v.w*scale + shift;
      *(float4*)(xt + r*36 + dd) = v;
    }
    __syncthreads();
    #pragma unroll
    for (int dd4 = 0; dd4 < 8; ++dd4) {
      const int dd = dd4*4;
      float4 w4[4], a[4];
      #pragma unroll
      for (int j=0;j<4;j++) w4[j] = *(const float4*)(ut + (kg+8*j)*132 + d0 + dd);
      #pragma unroll
      for (int i=0;i<4;i++) a[i]  = *(const float4*)(xt + (rg+32*i)*36 + dd);
      #pragma unroll
      for (int i=0;i<4;i++)
        #pragma unroll
        for (int j=0;j<4;j++)
          acc[i][j] += a[i].x*w4[j].x + a[i].y*w4[j].y + a[i].z*w4[j].z + a[i].w*w4[j].w;
    }
  }
  __syncthreads();
  #pragma unroll
  for (int i=0;i<4;i++) {                 // x_p = relu(acc) -> xt alias
    const int r = rg + 32*i;
    #pragma unroll
    for (int j=0;j<4;j++)
      xt[r*36 + (kg + 8*j)] = fmaxf(acc[i][j], 0.f);
  }
  __syncthreads();
  // I phase
  const int rg2 = t >> 2;                 // rows r = rg2 + 64*i, i<2
  const int jg  = t & 3;
  float iacc[2][10];
  #pragma unroll
  for (int i=0;i<2;i++)
    #pragma unroll
    for (int s=0;s<10;s++) iacc[i][s] = 0.f;
  #pragma unroll
  for (int kc=0;kc<8;kc++) {
    const int kkk = kc*4;
    float4 ypv[10];
    #pragma unroll
    for (int s=0;s<10;s++) ypv[s] = *(const float4*)(yp_l + (jg+4*s)*36 + kkk);
    #pragma unroll
    for (int i=0;i<2;i++) {
      float4 xv = *(const float4*)(xt + (rg2+64*i)*36 + kkk);
      #pragma unroll
      for (int s=0;s<10;s++)
        iacc[i][s] += xv.x*ypv[s].x + xv.y*ypv[s].y + xv.z*ypv[s].z + xv.w*ypv[s].w;
    }
  }
  if (MODE == 0) {
    #pragma unroll
    for (int s=0;s<10;s++) {              // block max per j (I >= 0)
      float m = fmaxf(iacc[0][s], iacc[1][s]);
      atomicMax((int*)&redm[jg + 4*s], __float_as_int(m));
    }
    __syncthreads();
    float es[10];
    #pragma unroll
    for (int s=0;s<10;s++) {              // partial sumexp
      float M = redm[jg + 4*s];
      es[s] = __expf(iacc[0][s] - M) + __expf(iacc[1][s] - M);
    }
    #pragma unroll
    for (int s=0;s<10;s++) {              // reduce over rg2 lanes (stride 4)
      es[s] += __shfl_xor(es[s], 4);
      es[s] += __shfl_xor(es[s], 8);
      es[s] += __shfl_xor(es[s], 16);
      es[s] += __shfl_xor(es[s], 32);
    }
    const int lane = t & 63, wv = t >> 6;
    if (lane < 4) {
      #pragma unroll
      for (int s=0;s<10;s++) sred[wv*40 + lane + 4*s] = es[s];
    }
    float* itile = ut;                    // ut dead -> 64x44 transpose staging
    #pragma unroll
    for (int i=0;i<2;i++) {
      __syncthreads();
      #pragma unroll
      for (int s=0;s<10;s++) itile[rg2*44 + jg + 4*s] = iacc[i][s];
      __syncthreads();
      #pragma unroll
      for (int u2=0; u2<10; ++u2) {       // coalesced copy to global
        int f = t + 256*u2;
        int r = f / 40, j = f - r*40;
        Iout[(rowbase + 64*i + r)*JJ + j] = itile[r*44 + j];
      }
    }
    __syncthreads();
    if (t < 40) {
      float stt = sred[t] + sred[40+t] + sred[80+t] + sred[120+t];
      Pm[((size_t)b*40 + t)*32 + blk] = redm[t];
      Ps[((size_t)b*40 + t)*32 + blk] = stt;
    }
  } else {
    #pragma unroll
    for (int i=0;i<2;i++) {
      float oa = 0.f;
      #pragma unroll
      for (int s=0;s<10;s++) oa += iacc[i][s]*iacc[i][s];
      oa += __shfl_xor(oa, 1);
      oa += __shfl_xor(oa, 2);
      if (jg == 0) outp[rowbase + rg2 + 64*i] = 1.f/(1.f + __expf(-oa));
    }
  }
}

// ---------------------------------------------------------------------------
// K5: combine per-block (m,s) partials -> global (M, S) per (graph, j)
// ---------------------------------------------------------------------------
__global__ void k_comb(const float* __restrict__ Pm, const float* __restrict__ Ps,
                       float* __restrict__ Mg, float* __restrict__ Sg) {
  const int b = blockIdx.x, j = threadIdx.x;
  if (j < 40) {
    const float* pm = Pm + ((size_t)b*40 + j)*32;
    const float* ps = Ps + ((size_t)b*40 + j)*32;
    float M = 0.f;
    #pragma unroll
    for (int k=0;k<32;k++) M = fmaxf(M, pm[k]);
    float S = 0.f;
    #pragma unroll
    for (int k=0;k<32;k++) S += ps[k]*__expf(pm[k]-M);
    Mg[b*40+j] = M;
    Sg[b*40+j] = S;
  }
}

// ---------------------------------------------------------------------------
// K6: e = exp(I-M)/S; h = relu(e@yp); h2 = h@V^T; z = sigm([x,h2].gW + gb);
//     x = (1-z)x + z*h2. 64 rows/block, aliased LDS (34.1 KB -> 4/CU), grid 2048.
// ---------------------------------------------------------------------------
__global__ __launch_bounds__(256,4)
void k_update(float* __restrict__ x, const float* __restrict__ Ibuf,
              const float* __restrict__ yp, const float* __restrict__ V,
              const float* __restrict__ gw, const float* __restrict__ gb,
              const float* __restrict__ Mg, const float* __restrict__ Sg,
              const float* __restrict__ nrm, const int normFlag) {
  __shared__ float uni[128*36];           // e_l (64x40) phase A/B, then v_l (128x36)
  __shared__ float h_l[64*36];
  __shared__ float ypt[32*40];
  __shared__ float M_l[40], Si_l[40];
  __shared__ float gx_l[128], gh_l[128];
  const int t = threadIdx.x;
  const int bid = blockIdx.x;
  const int b   = bid >> 6;               // 64 blocks per graph
  const int blk = bid & 63;
  const size_t rowbase = (size_t)b*NPG + blk*64;
  float scale = 1.f, shift = 0.f;
  if (normFlag) { scale = nrm[1]; shift = -nrm[0]*nrm[1]; }
  if (t < 40) { M_l[t] = Mg[b*40 + t]; Si_l[t] = 1.f / Sg[b*40 + t]; }
  if (t < 128) gx_l[t] = gw[t];
  else gh_l[t-128] = gw[t];
  for (int f4 = t; f4 < 320; f4 += 256) { // yp[b] -> ypt[k][j]
    int f = f4*4;
    int j = f >> 5;
    float4 v = *(const float4*)(yp + (size_t)b*(JJ*KK) + f);
    int k = f & 31;
    ypt[(k+0)*40 + j] = v.x;
    ypt[(k+1)*40 + j] = v.y;
    ypt[(k+2)*40 + j] = v.z;
    ypt[(k+3)*40 + j] = v.w;
  }
  __syncthreads();
  for (int f4 = t; f4 < 640; f4 += 256) { // e staging (64x40)
    int n = f4 / 10, j4 = (f4 - 10*n)*4;
    float4 v = *(const float4*)(Ibuf + (rowbase + n)*JJ + j4);
    float4 e;
    e.x = __expf(v.x - M_l[j4+0]) * Si_l[j4+0];
    e.y = __expf(v.y - M_l[j4+1]) * Si_l[j4+1];
    e.z = __expf(v.z - M_l[j4+2]) * Si_l[j4+2];
    e.w = __expf(v.w - M_l[j4+3]) * Si_l[j4+3];
    *(float4*)(uni + n*40 + j4) = e;
  }
  __syncthreads();
  { // phase B: h[n][k] = relu(sum_j e*yp)
    const int rg = t >> 3;                // r = rg + 32*i, i<2
    const int kg = t & 7;                 // k = kg + 8*j2, j2<4
    float hacc[2][4];
    #pragma unroll
    for (int i=0;i<2;i++)
      #pragma unroll
      for (int j2=0;j2<4;j2++) hacc[i][j2] = 0.f;
    #pragma unroll
    for (int jc=0;jc<10;jc++) {
      const int jj = jc*4;
      float4 yv[4];
      #pragma unroll
      for (int j2=0;j2<4;j2++) yv[j2] = *(const float4*)(ypt + (kg+8*j2)*40 + jj);
      #pragma unroll
      for (int i=0;i<2;i++) {
        float4 ev = *(const float4*)(uni + (rg+32*i)*40 + jj);
        #pragma unroll
        for (int j2=0;j2<4;j2++)
          hacc[i][j2] += ev.x*yv[j2].x + ev.y*yv[j2].y + ev.z*yv[j2].z + ev.w*yv[j2].w;
      }
    }
    #pragma unroll
    for (int i=0;i<2;i++)
      #pragma unroll
      for (int j2=0;j2<4;j2++)
        h_l[(rg+32*i)*36 + kg + 8*j2] = fmaxf(hacc[i][j2], 0.f);
  }
  __syncthreads();
  #pragma unroll
  for (int s=0;s<4;s++) {                 // stage V into uni (e dead)
    int f = (t + 256*s)*4;
    *(float4*)(uni + (f>>5)*36 + (f&31)) = *(const float4*)(V + f);
  }
  __syncthreads();
  // phase C: h2 = h@V^T, gate, blend; rows = rg3*4+i keeps LDS reads 2-way
  const int rg3 = t >> 4;                 // rows rg3*4 + i, i<4
  const int cg  = t & 15;                 // cols cg + 16*j3, j3<8
  float h2[4][8];
  #pragma unroll
  for (int i=0;i<4;i++)
    #pragma unroll
    for (int j3=0;j3<8;j3++) h2[i][j3] = 0.f;
  #pragma unroll
  for (int kc=0;kc<8;kc++) {
    const int kk2 = kc*4;
    float4 vv[8];
    #pragma unroll
    for (int j3=0;j3<8;j3++) vv[j3] = *(const float4*)(uni + (cg+16*j3)*36 + kk2);
    #pragma unroll
    for (int i=0;i<4;i++) {
      float4 hv = *(const float4*)(h_l + (rg3*4+i)*36 + kk2);
      #pragma unroll
      for (int j3=0;j3<8;j3++)
        h2[i][j3] += hv.x*vv[j3].x + hv.y*vv[j3].y + hv.z*vv[j3].z + hv.w*vv[j3].w;
    }
  }
  float xn[4][8];
  float gpv[4];
  #pragma unroll
  for (int i=0;i<4;i++) {
    float g = 0.f;
    const size_t rr = (rowbase + rg3*4 + i)*C;
    #pragma unroll
    for (int j3=0;j3<8;j3++) {
      const int c = cg + 16*j3;
      float xv = x[rr + c]*scale + shift;
      xn[i][j3] = xv;
      g += gx_l[c]*xv + gh_l[c]*h2[i][j3];
    }
    gpv[i] = g;
  }
  #pragma unroll
  for (int i=0;i<4;i++) {                 // reduce over the 16 cg lanes
    gpv[i] += __shfl_xor(gpv[i], 1);
    gpv[i] += __shfl_xor(gpv[i], 2);
    gpv[i] += __shfl_xor(gpv[i], 4);
    gpv[i] += __shfl_xor(gpv[i], 8);
  }
  const float gbv = gb[0];
  #pragma unroll
  for (int i=0;i<4;i++) {
    const float z = 1.f/(1.f + __expf(-(gpv[i] + gbv)));
    const size_t rr = (rowbase + rg3*4 + i)*C;
    #pragma unroll
    for (int j3=0;j3<8;j3++) {
      const int c = cg + 16*j3;
      x[rr + c] = (1.f - z)*xn[i][j3] + z*h2[i][j3];
    }
  }
}

extern "C" void kernel_launch(void* const* d_in, const int* in_sizes, int n_in,
                              void* d_out, int out_size, void* d_ws, size_t ws_size,
                              hipStream_t stream) {
  const float* nf  = (const float*)d_in[0];
  const float* fe  = (const float*)d_in[1];
  const float* W   = (const float*)d_in[2];
  const float* bin = (const float*)d_in[3];
  const float* U   = (const float*)d_in[4];
  const float* V   = (const float*)d_in[5];
  const float* q   = (const float*)d_in[6];
  const float* gw  = (const float*)d_in[7];
  const float* gb  = (const float*)d_in[8];
  float* out = (float*)d_out;
  float* wf  = (float*)d_ws;

  float*  X   = wf + X_OFF;
  float*  Ib  = wf + I_OFF;
  float*  TY  = wf + TY_OFF;
  float*  YP  = wf + YP_OFF;
  float*  PM  = wf + PM_OFF;
  float*  PS  = wf + PS_OFF;
  float*  MG  = wf + MG_OFF;
  float*  SG  = wf + SG_OFF;
  double* ST  = (double*)(wf + ST_OFF);
  float*  NRM = wf + NRM_OFF;

  hipMemsetAsync(ST, 0, 8*sizeof(float), stream);   // only stats need zeroing

  k_gemm_in<<<NTOT/64, 256, 0, stream>>>(nf, W, bin, X, ST);
  k_gemm_in<<<YROWS/64, 256, 0, stream>>>(fe, W, bin, TY, ST+2);
  k_stats<<<1, 64, 0, stream>>>(ST, NRM);
  k_yp<<<YROWS/32, 256, 0, stream>>>(TY, V, q, NRM, YP);

  // layer 0
  k_xpI<0><<<1024, 256, 0, stream>>>(X, U, YP, NRM, Ib, PM, PS, nullptr, 1);
  k_comb<<<32, 64, 0, stream>>>(PM, PS, MG, SG);
  k_update<<<2048, 256, 0, stream>>>(X, Ib, YP, V, gw, gb, MG, SG, NRM, 1);
  // layer 1
  k_xpI<0><<<1024, 256, 0, stream>>>(X, U, YP, NRM, Ib, PM, PS, nullptr, 0);
  k_comb<<<32, 64, 0, stream>>>(PM, PS, MG, SG);
  k_update<<<2048, 256, 0, stream>>>(X, Ib, YP, V, gw, gb, MG, SG, NRM, 0);
  // layer 2 (final): out = sigmoid(sum_j I^2), no I materialization
  k_xpI<1><<<1024, 256, 0, stream>>>(X, U, YP, NRM, nullptr, nullptr, nullptr, out, 0);
}

// Round 6
// 469.776 us; speedup vs baseline: 1.2199x; 1.0100x over previous
//
#include <hip/hip_runtime.h>
#include <math.h>

namespace {
constexpr int BB = 32, NPG = 4096, NTOT = BB*NPG, C = 128, FIN = 64, KK = 32, JJ = 40;
constexpr int YROWS = BB*JJ; // 1280
constexpr float EPS = 1e-5f;

// workspace layout (float offsets). All fp32 (numerics-identical to R2).
constexpr size_t X_OFF   = 0;                                  // NTOT*128
constexpr size_t I_OFF   = (size_t)NTOT*C;                     // NTOT*40
constexpr size_t TY_OFF  = I_OFF + (size_t)NTOT*JJ;            // 1280*128
constexpr size_t YP_OFF  = TY_OFF + (size_t)YROWS*C;           // 1280*32
constexpr size_t PM_OFF  = YP_OFF + (size_t)YROWS*KK;          // 32*40*32
constexpr size_t PS_OFF  = PM_OFF + 40960;                     // 32*40*32
constexpr size_t ST_OFF  = PS_OFF + 40960;                     // 4 doubles (even offset)
}

// ---------------------------------------------------------------------------
// K1: out[r][c] = in[r][0:64] . W[c][0:64] + b[c]; accumulate sum/sumsq (double).
// 64 rows/block, 256 thr, 4x8 register tile, XOR-swizzled LDS (48 KB -> 3/CU).
// ---------------------------------------------------------------------------
__global__ __launch_bounds__(256,3)
void k_gemm_in(const float* __restrict__ inp, const float* __restrict__ W,
               const float* __restrict__ bias, float* __restrict__ outp,
               double* __restrict__ stats) {
  __shared__ float in_t[64*64];          // 16384 B
  __shared__ float w_l[128*64];          // 32768 B
  __shared__ double dred[8];
  const int t = threadIdx.x;
  const int r0 = blockIdx.x * 64;
  #pragma unroll
  for (int s = 0; s < 4; ++s) {
    int f = (t + 256*s) * 4;
    int r = f >> 6, d = f & 63;
    float4 v = *(const float4*)(inp + (size_t)r0*FIN + f);
    *(float4*)(in_t + r*64 + (d ^ ((r & 7) * 8))) = v;
  }
  #pragma unroll
  for (int s = 0; s < 8; ++s) {
    int f = (t + 256*s) * 4;
    int r = f >> 6, d = f & 63;
    float4 w = *(const float4*)(W + f);
    *(float4*)(w_l + r*64 + (d ^ ((r & 7) * 8))) = w;
  }
  __syncthreads();
  const int rg = t >> 4;                 // rows r = rg + 16*i, i<4
  const int cg = t & 15;                 // cols c = cg + 16*j, j<8
  const int swi = (rg & 7) * 8;
  const int sww = (cg & 7) * 8;
  float acc[4][8];
  #pragma unroll
  for (int i=0;i<4;i++)
    #pragma unroll
    for (int j=0;j<8;j++) acc[i][j] = 0.f;
  #pragma unroll
  for (int dc = 0; dc < 16; ++dc) {
    const int d = dc*4;
    const int di = d ^ swi, dw = d ^ sww;
    float4 a[4], w4[8];
    #pragma unroll
    for (int i=0;i<4;i++) a[i]  = *(const float4*)(in_t + (rg+16*i)*64 + di);
    #pragma unroll
    for (int j=0;j<8;j++) w4[j] = *(const float4*)(w_l  + (cg+16*j)*64 + dw);
    #pragma unroll
    for (int i=0;i<4;i++)
      #pragma unroll
      for (int j=0;j<8;j++)
        acc[i][j] += a[i].x*w4[j].x + a[i].y*w4[j].y + a[i].z*w4[j].z + a[i].w*w4[j].w;
  }
  double ds = 0.0, dss = 0.0;
  #pragma unroll
  for (int i=0;i<4;i++) {
    const size_t r = (size_t)r0 + rg + 16*i;
    #pragma unroll
    for (int j=0;j<8;j++) {
      const int c = cg + 16*j;
      float v = acc[i][j] + bias[c];
      outp[r*C + c] = v;
      ds += (double)v; dss += (double)v*(double)v;
    }
  }
  #pragma unroll
  for (int off = 32; off > 0; off >>= 1) {
    ds  += __shfl_down(ds, off);
    dss += __shfl_down(dss, off);
  }
  if ((t & 63) == 0) { dred[(t>>6)*2] = ds; dred[(t>>6)*2+1] = dss; }
  __syncthreads();
  if (t == 0) {
    atomicAdd(stats+0, dred[0]+dred[2]+dred[4]+dred[6]);
    atomicAdd(stats+1, dred[1]+dred[3]+dred[5]+dred[7]);
  }
}

// ---------------------------------------------------------------------------
// K3: y_p[row][k] = relu(q[k]*relu( ((ty-my)*ry) . V[:,k] )); 32 rows/block.
// LN stats derived inline from ST (k_stats folded in).
// ---------------------------------------------------------------------------
__global__ __launch_bounds__(256)
void k_yp(const float* __restrict__ ty, const float* __restrict__ V,
          const float* __restrict__ q, const double* __restrict__ ST,
          float* __restrict__ yp) {
  __shared__ float ty_l[32*132];
  __shared__ float vt_l[32*132];
  __shared__ float q_l[32];
  const int t = threadIdx.x;
  const int r0 = blockIdx.x * 32;
  double cy = (double)YROWS * (double)C;
  double myd = ST[2]/cy, vy = ST[3]/cy - myd*myd;
  const float my = (float)myd;
  const float ry = (float)(1.0/sqrt(vy + (double)EPS));
  #pragma unroll
  for (int s=0;s<4;s++) {
    int f = (t + 256*s)*4;
    int r = f >> 7, d = f & 127;
    float4 v = *(const float4*)(ty + (size_t)(r0+r)*C + d);
    v.x = (v.x-my)*ry; v.y = (v.y-my)*ry; v.z = (v.z-my)*ry; v.w = (v.w-my)*ry;
    *(float4*)(ty_l + r*132 + d) = v;
  }
  #pragma unroll
  for (int s=0;s<4;s++) {                 // V[d][k] -> vt[k][d]
    int f = (t + 256*s)*4;
    int d = f >> 5, k = f & 31;
    float4 v = *(const float4*)(V + f);
    vt_l[(k+0)*132 + d] = v.x;
    vt_l[(k+1)*132 + d] = v.y;
    vt_l[(k+2)*132 + d] = v.z;
    vt_l[(k+3)*132 + d] = v.w;
  }
  if (t < 32) q_l[t] = q[t];
  __syncthreads();
  const int rg = t >> 3;                  // one row
  const int kg = t & 7;                   // k = kg + 8*j
  float acc[4] = {0.f,0.f,0.f,0.f};
  #pragma unroll
  for (int dc=0; dc<32; ++dc) {
    const int d = dc*4;
    float4 a = *(const float4*)(ty_l + rg*132 + d);
    #pragma unroll
    for (int j=0;j<4;j++) {
      float4 w = *(const float4*)(vt_l + (kg+8*j)*132 + d);
      acc[j] += a.x*w.x + a.y*w.y + a.z*w.z + a.w*w.w;
    }
  }
  #pragma unroll
  for (int j=0;j<4;j++) {
    const int k = kg + 8*j;
    float v = fmaxf(acc[j], 0.f);
    v = fmaxf(q_l[k]*v, 0.f);
    yp[(size_t)(r0+rg)*KK + k] = v;
  }
}

// ---------------------------------------------------------------------------
// K4 (MODE 0): x_p = relu(xn@U), I = x_p@yp^T -> I fp32 + per-block (m, sumexp)
// K4 (MODE 1): out = sigmoid(sum_j I^2) [final-layer identity], no I write
// All fp32. Partitioned BUF: xst(128x20)|ut(32x132) -> x_p(128x36) -> itile(64x44).
// 33.7 KB LDS -> 4/CU, __launch_bounds__(256,4). Grid 1024.
// ---------------------------------------------------------------------------
template<int MODE>
__global__ __launch_bounds__(256,4)
void k_xpI(const float* __restrict__ X, const float* __restrict__ U,
           const float* __restrict__ yp, const double* __restrict__ ST,
           float* __restrict__ Ibf, float* __restrict__ Pm,
           float* __restrict__ Ps, float* __restrict__ outp, const int normFlag) {
  __shared__ float BUF[6784];             // 27136 B, phase-aliased
  __shared__ float yp_l[40*36];           // 5760 B
  __shared__ float redm[40];
  __shared__ float sred[160];
  float* xst = BUF;                       // 128x20 during GEMM
  float* ut  = BUF + 2560;                // 32x132 during GEMM
  const int t = threadIdx.x;
  const int bid = blockIdx.x;
  const int b   = bid >> 5;               // 32 blocks per graph
  const int blk = bid & 31;
  const size_t rowbase = (size_t)b*NPG + (size_t)blk*128;
  float sc = 1.f, sh = 0.f;
  if (normFlag) {
    double cx = (double)NTOT * (double)C;
    double mx = ST[0]/cx, vx = ST[1]/cx - mx*mx;
    float mxf = (float)mx, rx = (float)(1.0/sqrt(vx + (double)EPS));
    sc = rx; sh = -mxf*rx;
  }
  #pragma unroll
  for (int s=0;s<4;s++) {                 // U[d][k] -> ut[k][d] fp32
    int f = (t + 256*s)*4;
    int d = f >> 5, k = f & 31;
    float4 v = *(const float4*)(U + f);
    ut[(k+0)*132 + d] = v.x;
    ut[(k+1)*132 + d] = v.y;
    ut[(k+2)*132 + d] = v.z;
    ut[(k+3)*132 + d] = v.w;
  }
  for (int f4 = t; f4 < 320; f4 += 256) {
    int f = f4*4;
    *(float4*)(yp_l + (f>>5)*36 + (f&31)) = *(const float4*)(yp + (size_t)b*(JJ*KK) + f);
  }
  if (MODE == 0 && t < 40) redm[t] = 0.f;

  const int rg = t >> 3;                  // rows r = rg + 32*i, i<4
  const int kg = t & 7;                   // k = kg + 8*j, j<4
  float acc[4][4];
  #pragma unroll
  for (int i=0;i<4;i++)
    #pragma unroll
    for (int j=0;j<4;j++) acc[i][j] = 0.f;

  for (int cc = 0; cc < 8; ++cc) {        // 16-col chunks, d ascending (R2 order)
    const int d0 = cc*16;
    __syncthreads();
    #pragma unroll
    for (int s=0;s<2;s++) {               // stage 128x16 normalized fp32
      int idx = t + 256*s;                // float4 index in 512
      int row = idx >> 2, q4 = idx & 3;
      float4 v = *(const float4*)(X + (rowbase+row)*C + d0 + 4*q4);
      v.x = v.x*sc + sh; v.y = v.y*sc + sh;
      v.z = v.z*sc + sh; v.w = v.w*sc + sh;
      *(float4*)(xst + row*20 + 4*q4) = v;
    }
    __syncthreads();
    #pragma unroll
    for (int dd4 = 0; dd4 < 4; ++dd4) {
      const int dd = dd4*4;
      float4 a[4];
      #pragma unroll
      for (int i=0;i<4;i++) a[i] = *(const float4*)(xst + (rg+32*i)*20 + dd);
      #pragma unroll
      for (int j=0;j<4;j++) {
        float4 w4 = *(const float4*)(ut + (kg+8*j)*132 + d0 + dd);
        #pragma unroll
        for (int i=0;i<4;i++)
          acc[i][j] += a[i].x*w4.x + a[i].y*w4.y + a[i].z*w4.z + a[i].w*w4.w;
      }
    }
  }
  __syncthreads();                        // all GEMM LDS reads done
  #pragma unroll
  for (int i=0;i<4;i++)                   // x_p = relu(acc) -> BUF (stride 36)
    #pragma unroll
    for (int j=0;j<4;j++)
      BUF[(rg+32*i)*36 + kg + 8*j] = fmaxf(acc[i][j], 0.f);
  __syncthreads();
  // I phase (two halves of 5 j-cols; k ascending per element = R2 order)
  const int rg2 = t >> 2;                 // rows r = rg2 + 64*i, i<2
  const int jg  = t & 3;
  float ia[2][10];
  #pragma unroll
  for (int i=0;i<2;i++)
    #pragma unroll
    for (int s=0;s<10;s++) ia[i][s] = 0.f;
  #pragma unroll
  for (int half=0; half<2; ++half) {
    #pragma unroll
    for (int kc=0;kc<8;kc++) {
      const int kk4 = kc*4;
      float4 yv[5];
      #pragma unroll
      for (int s=0;s<5;s++) yv[s] = *(const float4*)(yp_l + (jg+4*(half*5+s))*36 + kk4);
      #pragma unroll
      for (int i=0;i<2;i++) {
        float4 xv = *(const float4*)(BUF + (rg2+64*i)*36 + kk4);
        #pragma unroll
        for (int s=0;s<5;s++)
          ia[i][half*5+s] += xv.x*yv[s].x + xv.y*yv[s].y + xv.z*yv[s].z + xv.w*yv[s].w;
      }
    }
  }
  if (MODE == 0) {
    #pragma unroll
    for (int s=0;s<10;s++)                // block max per j (I >= 0)
      atomicMax((int*)&redm[jg+4*s], __float_as_int(fmaxf(ia[0][s], ia[1][s])));
    __syncthreads();
    float es[10];
    #pragma unroll
    for (int s=0;s<10;s++) {
      float M = redm[jg + 4*s];
      es[s] = __expf(ia[0][s] - M) + __expf(ia[1][s] - M);
    }
    #pragma unroll
    for (int s=0;s<10;s++) {
      es[s] += __shfl_xor(es[s], 4);  es[s] += __shfl_xor(es[s], 8);
      es[s] += __shfl_xor(es[s], 16); es[s] += __shfl_xor(es[s], 32);
    }
    {
      const int lane = t & 63, wv = t >> 6;
      if (lane < 4) {
        #pragma unroll
        for (int s=0;s<10;s++) sred[wv*40 + lane + 4*s] = es[s];
      }
    }
    __syncthreads();
    if (t < 40) {
      size_t po = ((size_t)b*40 + t)*32 + blk;
      Pm[po] = redm[t];
      Ps[po] = sred[t]+sred[40+t]+sred[80+t]+sred[120+t];
    }
    float* itile = BUF;                   // x_p reads done -> 64x44 staging
    #pragma unroll
    for (int i=0;i<2;i++) {
      __syncthreads();
      #pragma unroll
      for (int s=0;s<10;s++) itile[rg2*44 + jg + 4*s] = ia[i][s];
      __syncthreads();
      #pragma unroll
      for (int u=0;u<10;u++) {            // 2560 floats coalesced
        int f = t + 256*u;
        int r = f / 40, j = f - r*40;
        Ibf[(rowbase + 64*i + r)*JJ + j] = itile[r*44 + j];
      }
    }
  } else {
    #pragma unroll
    for (int i=0;i<2;i++) {
      float oa = 0.f;
      #pragma unroll
      for (int s=0;s<10;s++) oa += ia[i][s]*ia[i][s];
      oa += __shfl_xor(oa,1); oa += __shfl_xor(oa,2);
      if (jg==0) outp[rowbase + rg2 + 64*i] = 1.f/(1.f+__expf(-oa));
    }
  }
}

// ---------------------------------------------------------------------------
// K6: e = exp(I-M)/S; h = relu(e@yp); h2 = h@V^T; z = sigm([x,h2].gW + gb);
//     x = (1-z)x + z*h2. All fp32. (M,S) combined inline from PM/PS (k_comb
//     folded in); nrm inline from ST. 64 rows/block, 34.4 KB -> 4/CU, grid 2048.
// ---------------------------------------------------------------------------
__global__ __launch_bounds__(256,4)
void k_update(float* __restrict__ x, const float* __restrict__ Ibf,
              const float* __restrict__ yp, const float* __restrict__ V,
              const float* __restrict__ gw, const float* __restrict__ gb,
              const float* __restrict__ Pm, const float* __restrict__ Ps,
              const double* __restrict__ ST, const int normFlag) {
  __shared__ float uni[128*36];           // e (64x40) phases A/B, then V (128x36)
  __shared__ float h_l[64*36];
  __shared__ float ypt[32*40];
  __shared__ float M_l[40], Si_l[40];
  __shared__ float gx_l[128], gh_l[128];
  const int t = threadIdx.x;
  const int bid = blockIdx.x;
  const int b   = bid >> 6;               // 64 blocks per graph
  const int blk = bid & 63;
  const size_t rowbase = (size_t)b*NPG + (size_t)blk*64;
  float sc = 1.f, sh = 0.f;
  if (normFlag) {
    double cx = (double)NTOT * (double)C;
    double mx = ST[0]/cx, vx = ST[1]/cx - mx*mx;
    float mxf = (float)mx, rx = (float)(1.0/sqrt(vx + (double)EPS));
    sc = rx; sh = -mxf*rx;
  }
  if (t < 40) {                           // inline k_comb
    const float* pm = Pm + ((size_t)b*40 + t)*32;
    const float* ps = Ps + ((size_t)b*40 + t)*32;
    float M = 0.f;
    #pragma unroll
    for (int k=0;k<32;k++) M = fmaxf(M, pm[k]);
    float S = 0.f;
    #pragma unroll
    for (int k=0;k<32;k++) S += ps[k]*__expf(pm[k]-M);
    M_l[t] = M; Si_l[t] = 1.f/S;
  }
  if (t < 128) gx_l[t] = gw[t];
  else gh_l[t-128] = gw[t];
  for (int f4 = t; f4 < 320; f4 += 256) { // yp[b] -> ypt[k][j]
    int f = f4*4;
    int j = f >> 5;
    float4 v = *(const float4*)(yp + (size_t)b*(JJ*KK) + f);
    int k = f & 31;
    ypt[(k+0)*40 + j] = v.x;
    ypt[(k+1)*40 + j] = v.y;
    ypt[(k+2)*40 + j] = v.z;
    ypt[(k+3)*40 + j] = v.w;
  }
  __syncthreads();
  for (int f4 = t; f4 < 640; f4 += 256) { // e staging (64x40) from fp32 I
    int f = f4*4;
    int n = f / 40, j = f - n*40;
    float4 v = *(const float4*)(Ibf + (rowbase + n)*JJ + j);
    float4 e;
    e.x = __expf(v.x - M_l[j+0]) * Si_l[j+0];
    e.y = __expf(v.y - M_l[j+1]) * Si_l[j+1];
    e.z = __expf(v.z - M_l[j+2]) * Si_l[j+2];
    e.w = __expf(v.w - M_l[j+3]) * Si_l[j+3];
    *(float4*)(uni + n*40 + j) = e;
  }
  __syncthreads();
  { // phase B: h[n][k] = relu(sum_j e*yp)
    const int rg = t >> 3;                // r = rg + 32*i, i<2
    const int kg = t & 7;                 // k = kg + 8*j2, j2<4
    float hacc[2][4];
    #pragma unroll
    for (int i=0;i<2;i++)
      #pragma unroll
      for (int j2=0;j2<4;j2++) hacc[i][j2] = 0.f;
    #pragma unroll
    for (int jc=0;jc<10;jc++) {
      const int jj = jc*4;
      float4 yv[4];
      #pragma unroll
      for (int j2=0;j2<4;j2++) yv[j2] = *(const float4*)(ypt + (kg+8*j2)*40 + jj);
      #pragma unroll
      for (int i=0;i<2;i++) {
        float4 ev = *(const float4*)(uni + (rg+32*i)*40 + jj);
        #pragma unroll
        for (int j2=0;j2<4;j2++)
          hacc[i][j2] += ev.x*yv[j2].x + ev.y*yv[j2].y + ev.z*yv[j2].z + ev.w*yv[j2].w;
      }
    }
    #pragma unroll
    for (int i=0;i<2;i++)
      #pragma unroll
      for (int j2=0;j2<4;j2++)
        h_l[(rg+32*i)*36 + kg + 8*j2] = fmaxf(hacc[i][j2], 0.f);
  }
  __syncthreads();
  #pragma unroll
  for (int s=0;s<4;s++) {                 // stage V into uni (e dead)
    int f = (t + 256*s)*4;
    *(float4*)(uni + (f>>5)*36 + (f&31)) = *(const float4*)(V + f);
  }
  __syncthreads();
  // phase C: h2 = h@V^T
  const int rg3 = t >> 4;                 // rows rg3*4 + i, i<4
  const int cg  = t & 15;                 // cols cg + 16*j3, j3<8
  float h2[4][8];
  #pragma unroll
  for (int i=0;i<4;i++)
    #pragma unroll
    for (int j3=0;j3<8;j3++) h2[i][j3] = 0.f;
  #pragma unroll
  for (int kc=0;kc<8;kc++) {
    const int kk2 = kc*4;
    float4 vv[8];
    #pragma unroll
    for (int j3=0;j3<8;j3++) vv[j3] = *(const float4*)(uni + (cg+16*j3)*36 + kk2);
    #pragma unroll
    for (int i=0;i<4;i++) {
      float4 hv = *(const float4*)(h_l + (rg3*4+i)*36 + kk2);
      #pragma unroll
      for (int j3=0;j3<8;j3++)
        h2[i][j3] += hv.x*vv[j3].x + hv.y*vv[j3].y + hv.z*vv[j3].z + hv.w*vv[j3].w;
    }
  }
  float xn[4][8];
  float gpv[4];
  #pragma unroll
  for (int i=0;i<4;i++) {
    float g = 0.f;
    const size_t rr = (rowbase + rg3*4 + i)*C;
    #pragma unroll
    for (int j3=0;j3<8;j3++) {
      const int c = cg + 16*j3;
      float xv = x[rr + c]*sc + sh;
      xn[i][j3] = xv;
      g += gx_l[c]*xv + gh_l[c]*h2[i][j3];
    }
    gpv[i] = g;
  }
  #pragma unroll
  for (int i=0;i<4;i++) {                 // reduce over the 16 cg lanes
    gpv[i] += __shfl_xor(gpv[i], 1);
    gpv[i] += __shfl_xor(gpv[i], 2);
    gpv[i] += __shfl_xor(gpv[i], 4);
    gpv[i] += __shfl_xor(gpv[i], 8);
  }
  const float gbv = gb[0];
  #pragma unroll
  for (int i=0;i<4;i++) {
    const float z = 1.f/(1.f + __expf(-(gpv[i] + gbv)));
    const size_t rr = (rowbase + rg3*4 + i)*C;
    #pragma unroll
    for (int j3=0;j3<8;j3++) {
      const int c = cg + 16*j3;
      x[rr + c] = (1.f - z)*xn[i][j3] + z*h2[i][j3];
    }
  }
}

extern "C" void kernel_launch(void* const* d_in, const int* in_sizes, int n_in,
                              void* d_out, int out_size, void* d_ws, size_t ws_size,
                              hipStream_t stream) {
  const float* nf  = (const float*)d_in[0];
  const float* fe  = (const float*)d_in[1];
  const float* W   = (const float*)d_in[2];
  const float* bin = (const float*)d_in[3];
  const float* U   = (const float*)d_in[4];
  const float* V   = (const float*)d_in[5];
  const float* q   = (const float*)d_in[6];
  const float* gw  = (const float*)d_in[7];
  const float* gb  = (const float*)d_in[8];
  float* out = (float*)d_out;
  float* wf  = (float*)d_ws;

  float*  X   = wf + X_OFF;
  float*  Ibf = wf + I_OFF;
  float*  TY  = wf + TY_OFF;
  float*  YP  = wf + YP_OFF;
  float*  PM  = wf + PM_OFF;
  float*  PS  = wf + PS_OFF;
  double* ST  = (double*)(wf + ST_OFF);

  hipMemsetAsync(ST, 0, 4*sizeof(double), stream);

  k_gemm_in<<<NTOT/64, 256, 0, stream>>>(nf, W, bin, X, ST);
  k_gemm_in<<<YROWS/64, 256, 0, stream>>>(fe, W, bin, TY, ST+2);
  k_yp<<<YROWS/32, 256, 0, stream>>>(TY, V, q, ST, YP);

  // layer 0
  k_xpI<0><<<1024, 256, 0, stream>>>(X, U, YP, ST, Ibf, PM, PS, nullptr, 1);
  k_update<<<2048, 256, 0, stream>>>(X, Ibf, YP, V, gw, gb, PM, PS, ST, 1);
  // layer 1
  k_xpI<0><<<1024, 256, 0, stream>>>(X, U, YP, ST, Ibf, PM, PS, nullptr, 0);
  k_update<<<2048, 256, 0, stream>>>(X, Ibf, YP, V, gw, gb, PM, PS, ST, 0);
  // layer 2 (final): out = sigmoid(sum_j I^2)
  k_xpI<1><<<1024, 256, 0, stream>>>(X, U, YP, ST, nullptr, nullptr, nullptr, out, 0);
}